// Round 5
// baseline (346.662 us; speedup 1.0000x reference)
//
#include <hip/hip_runtime.h>

typedef unsigned short u16;
typedef __attribute__((ext_vector_type(8))) short s16x8;
typedef __attribute__((ext_vector_type(4))) float f32x4;
typedef __attribute__((ext_vector_type(16))) float f32x16;
typedef __attribute__((ext_vector_type(4))) unsigned short u16x4;
typedef __attribute__((ext_vector_type(2))) unsigned int u32x2;

#define MFMA16(a, b, c) __builtin_amdgcn_mfma_f32_16x16x32_bf16(a, b, c, 0, 0, 0)
#define MFMA32(a, b, c) __builtin_amdgcn_mfma_f32_32x32x16_bf16(a, b, c, 0, 0, 0)

__device__ __forceinline__ u16 f2bf(float f) {
  unsigned u = __builtin_bit_cast(unsigned, f);
  u += 0x7fffu + ((u >> 16) & 1u);  // RNE
  return (u16)(u >> 16);
}

// pack bf16(lo),bf16(hi) from two f32 (truncation) in ONE v_perm
__device__ __forceinline__ unsigned pkbf(float lo, float hi) {
  return __builtin_amdgcn_perm(__builtin_bit_cast(unsigned, hi),
                               __builtin_bit_cast(unsigned, lo), 0x07060302u);
}

__device__ __forceinline__ void async16(const void* g, void* l) {
  __builtin_amdgcn_global_load_lds(
      (const __attribute__((address_space(1))) void*)g,
      (__attribute__((address_space(3))) void*)l, 16, 0, 0);
}

__device__ __forceinline__ s16x8 ld8(const u16* p) { return *(const s16x8*)p; }

// log2(e) / sqrt(64) folded into Q at projection time
#define PRE 0.18033688011112042f

// ---------------- fused fp32 -> bf16 cast of all 5 tensors ----------------
__global__ __launch_bounds__(256) void cvt_all(
    const float* __restrict__ X, const float* __restrict__ Wq,
    const float* __restrict__ Wk, const float* __restrict__ Wv,
    const float* __restrict__ Wo, u16* __restrict__ out) {
  long e = (long)(blockIdx.x * 256 + threadIdx.x) * 4;
  const float* src;
  if (e < 8388608L) src = X + e;
  else if (e < 12582912L) src = Wq + (e - 8388608L);
  else if (e < 13631488L) src = Wk + (e - 12582912L);
  else if (e < 14680064L) src = Wv + (e - 13631488L);
  else src = Wo + (e - 14680064L);
  float4 v = *(const float4*)src;
  u16x4 o = {f2bf(v.x), f2bf(v.y), f2bf(v.z), f2bf(v.w)};
  *(u16x4*)(out + e) = o;
}

// ---------------- NT GEMM: C[m,n] = sum_k A[m,k]*B[n,k] ----------------
// 128xBN tile, BK=32, double-buffered LDS, one barrier per K-iter.
// BN=128 for QKV (rope epilogue needs 64-col wave span), BN=64 for OUT
// (grid doubles -> 4 blocks/CU latency hiding).
enum { EPI_QKV = 0, EPI_OUT = 1 };

template <int EPI, int BN>
__global__ __launch_bounds__(256) void gemm_nt(
    const u16* __restrict__ A, const u16* __restrict__ Bm,
    const float* __restrict__ cosp, const float* __restrict__ sinp,
    u16* __restrict__ Qo, u16* __restrict__ Ko, u16* __restrict__ Vo,
    float* __restrict__ Co, int K) {
  constexpr int BUF = 4096 + BN * 32;  // u16 per buffer (A | B)
  constexpr int NJ = BN / 32;          // acc cols per wave
  constexpr int NB = BN / 64;          // B staging chunks per thread
  __shared__ u16 SM[EPI == EPI_QKV ? 16384 : 2 * (4096 + BN * 32)];
  const int t = threadIdx.x;
  const int lane = t & 63;
  const int w = t >> 6, wm = w >> 1, wn = w & 1;
  const int quad = lane >> 4, c16 = lane & 15;
  const int m0 = blockIdx.y * 128, n0 = blockIdx.x * BN;

  f32x4 acc[4][NJ];
  const f32x4 zero = {0.f, 0.f, 0.f, 0.f};
#pragma unroll
  for (int i = 0; i < 4; ++i)
#pragma unroll
    for (int j = 0; j < NJ; ++j) acc[i][j] = zero;

  // staging: chunk c (16B) of an Rx32 tile holds global
  //   double-row dr=c>>3, k8=(c&7)^(dr&7) -> (row 2dr+(k8>>2), colchunk k8&3)
  const u16* gA[2];
  const u16* gB[NB];
  int lofA[2], lofB[NB];
#pragma unroll
  for (int p = 0; p < 2; ++p) {
    int c = t + p * 256;
    int dr = c >> 3, k8 = (c & 7) ^ (dr & 7);
    gA[p] = A + (size_t)(m0 + 2 * dr + (k8 >> 2)) * K + (k8 & 3) * 8;
    lofA[p] = c * 8;
  }
#pragma unroll
  for (int p = 0; p < NB; ++p) {
    int c = t + p * 256;
    int dr = c >> 3, k8 = (c & 7) ^ (dr & 7);
    gB[p] = Bm + (size_t)(n0 + 2 * dr + (k8 >> 2)) * K + (k8 & 3) * 8;
    lofB[p] = 4096 + c * 8;
  }

  // fragment LDS offsets (loop-invariant; toggle buffer by +BUF)
  int aoff[4], boff[NJ];
#pragma unroll
  for (int i = 0; i < 4; ++i) {
    int rowA = wm * 64 + i * 16 + c16;
    int drA = rowA >> 1;
    int chA = (((rowA & 1) << 2) | quad) ^ (drA & 7);
    aoff[i] = drA * 64 + chA * 8;
  }
#pragma unroll
  for (int j = 0; j < NJ; ++j) {
    int rowB = wn * (BN / 2) + j * 16 + c16;
    int drB = rowB >> 1;
    int chB = (((rowB & 1) << 2) | quad) ^ (drB & 7);
    boff[j] = 4096 + drB * 64 + chB * 8;
  }

  // prologue: stage buffer 0 with k-slab 0
#pragma unroll
  for (int p = 0; p < 2; ++p) async16(gA[p], &SM[lofA[p]]);
#pragma unroll
  for (int p = 0; p < NB; ++p) async16(gB[p], &SM[lofB[p]]);

  const int niter = K >> 5;
  for (int kt = 0; kt < niter; ++kt) {
    const int cb = (kt & 1) * BUF;
    __syncthreads();  // buf[cur] staged; prev reads of buf[nxt] done
    if (kt + 1 < niter) {
      const int nb = BUF - cb;
#pragma unroll
      for (int p = 0; p < 2; ++p) {
        gA[p] += 32;
        async16(gA[p], &SM[nb + lofA[p]]);
      }
#pragma unroll
      for (int p = 0; p < NB; ++p) {
        gB[p] += 32;
        async16(gB[p], &SM[nb + lofB[p]]);
      }
    }
    s16x8 af[4], bfr[NJ];
#pragma unroll
    for (int i = 0; i < 4; ++i) af[i] = ld8(&SM[cb + aoff[i]]);
#pragma unroll
    for (int j = 0; j < NJ; ++j) bfr[j] = ld8(&SM[cb + boff[j]]);
#pragma unroll
    for (int i = 0; i < 4; ++i)
#pragma unroll
      for (int j = 0; j < NJ; ++j) acc[i][j] = MFMA16(af[i], bfr[j], acc[i][j]);
  }

  if (EPI == EPI_OUT) {
#pragma unroll
    for (int i = 0; i < 4; ++i)
#pragma unroll
      for (int r = 0; r < 4; ++r) {
        int m = m0 + wm * 64 + i * 16 + quad * 4 + r;
        float* dst = Co + (size_t)m * 2048 + n0 + wn * (BN / 2) + c16;
#pragma unroll
        for (int j = 0; j < NJ; ++j) dst[j * 16] = acc[i][j][r];
      }
  } else if (n0 >= 2560) {
    // V zone: transpose via LDS -> coalesced 16B stores of V^T [B][8][64][S]
    __syncthreads();
#pragma unroll
    for (int i = 0; i < 4; ++i)
#pragma unroll
      for (int r = 0; r < 4; ++r) {
        int sl = wm * 64 + i * 16 + quad * 4 + r;
#pragma unroll
        for (int j = 0; j < 4; ++j) {
          int dl = wn * 64 + j * 16 + c16;
          SM[dl * 128 + (((sl >> 3) ^ (dl & 15)) * 8) + (sl & 7)] =
              f2bf(acc[i][j][r]);
        }
      }
    __syncthreads();
    int bb = m0 >> 11, m0s = m0 & 2047;
#pragma unroll
    for (int p = 0; p < 8; ++p) {
      int q = p * 256 + t;
      int dl = q >> 4, k = q & 15;
      s16x8 vrow = ld8(&SM[dl * 128 + ((k ^ (dl & 15)) * 8)]);
      int nab = n0 + dl;
      int kvh = (nab - 2560) >> 6, dh = nab & 63;
      *(s16x8*)(Vo + ((size_t)(bb * 8 + kvh) * 64 + dh) * 2048 + m0s + k * 8) =
          vrow;
    }
  } else {
    const int nbase = n0 + wn * 64;
#pragma unroll
    for (int i = 0; i < 4; ++i)
#pragma unroll
      for (int r = 0; r < 4; ++r) {
        int m = m0 + wm * 64 + i * 16 + quad * 4 + r;
        int b = m >> 11, s = m & 2047;
        if (nbase < 2048) {  // Q zone: rope + prescale, store [B][32][S][64]
          int h = nbase >> 6;
          size_t base = ((size_t)(b * 32 + h) * 2048 + s) * 64;
#pragma unroll
          for (int j = 0; j < 2; ++j) {
            int d = j * 16 + c16;
            float v1 = acc[i][j][r], v2 = acc[i][j + 2][r];
            float c1 = cosp[m * 64 + d], s1 = sinp[m * 64 + d];
            float c2 = cosp[m * 64 + d + 32], s2 = sinp[m * 64 + d + 32];
            Qo[base + d] = f2bf((v1 * c1 - v2 * s1) * PRE);
            Qo[base + d + 32] = f2bf((v2 * c2 + v1 * s2) * PRE);
          }
        } else {  // K zone: rope, store [B][8][S][64]
          int h = (nbase - 2048) >> 6;
          size_t base = ((size_t)(b * 8 + h) * 2048 + s) * 64;
#pragma unroll
          for (int j = 0; j < 2; ++j) {
            int d = j * 16 + c16;
            float v1 = acc[i][j][r], v2 = acc[i][j + 2][r];
            float c1 = cosp[m * 64 + d], s1 = sinp[m * 64 + d];
            float c2 = cosp[m * 64 + d + 32], s2 = sinp[m * 64 + d + 32];
            Ko[base + d] = f2bf(v1 * c1 - v2 * s1);
            Ko[base + d + 32] = f2bf(v2 * c2 + v1 * s2);
          }
        }
      }
  }
}

// ---------------- flash attention (causal, GQA), 32x32x16 MFMA ------------
// grid: (8 qt-pairs, 64 b*h). Block = 4 waves x 32 q-rows = BQ 128; BKV=64.
// S^T = K·Q^T (A=K from LDS once, B=Q in regs); C-layout: lane holds one
// q (lane&31) x 16 keys -> 4-consecutive-key reg-quads pack to ds_write_b64.
// O^T: A=V^T rows, B=P rows -> lane holds one q x 16 d; lacc is lane-local.
// Fixed-m (m=0) softmax: Q pre-scaled, exp2 can't overflow; masked -> 0.
__global__ __launch_bounds__(256) void attn(const u16* __restrict__ Q,
                                            const u16* __restrict__ Kg,
                                            const u16* __restrict__ Vg,
                                            u16* __restrict__ O) {
  __shared__ u16 Ks[2][4096];
  __shared__ u16 Vs[2][4096];
  __shared__ u16 Ps[8192];  // 4 waves x 32 q x 64 keys, 16B-chunk swizzled
  const int t = threadIdx.x;
  const int lane = t & 63;
  const int w = t >> 6;
  const int l31 = lane & 31;  // q-index within wave tile
  const int lh = lane >> 5;   // k-run selector
  const int bh = blockIdx.y;
  const int b = bh >> 5, h = bh & 31;
  const int kvh = h >> 2;  // G = 4

  const u16* Qbase = Q + ((size_t)(b * 32 + h) * 2048) * 64;
  const u16* Kbase = Kg + ((size_t)(b * 8 + kvh) * 2048) * 64;
  const u16* Vbase = Vg + ((size_t)(b * 8 + kvh) * 64) * 2048;

  // staging source offsets (row r, swizzled colchunk)
  const int sr0 = t >> 3, sc0 = ((t & 7) ^ (sr0 & 7)) * 8;
  const int sr1 = (t + 256) >> 3, sc1 = (((t + 256) & 7) ^ (sr1 & 7)) * 8;

  // fragment/addr precompute (row-XOR is l31&7 for K,V,P alike)
  int swz[4];  // read chunk offsets for dep=0..3
#pragma unroll
  for (int dep = 0; dep < 4; ++dep)
    swz[dep] = l31 * 64 + (((dep * 2 + lh) ^ (l31 & 7)) * 8);
  int wof[8];  // P-write offsets for chunk id 0..7 (mt*4+rq)
#pragma unroll
  for (int c8 = 0; c8 < 8; ++c8)
    wof[c8] = w * 2048 + l31 * 64 + ((c8 ^ (l31 & 7)) * 8) + 4 * lh;

  for (int ph = 0; ph < 2; ++ph) {
    const int qt = ph ? 15 - blockIdx.x : blockIdx.x;
    const int q0 = qt * 128;
    const int qw = q0 + w * 32;  // wave q base

    // Q B-frags (32x32x16 layout): Q[qw+l31][dep*16 + lh*8 + 0..7]
    s16x8 qb[4];
#pragma unroll
    for (int dep = 0; dep < 4; ++dep)
      qb[dep] = ld8(Qbase + (size_t)(qw + l31) * 64 + dep * 16 + lh * 8);

    f32x16 osum[2];
    float lacc = 0.f;
#pragma unroll
    for (int mt = 0; mt < 2; ++mt)
#pragma unroll
      for (int r = 0; r < 16; ++r) osum[mt][r] = 0.f;

    const int nkt = 2 * qt + 2;

    __syncthreads();  // previous phase's LDS reads done before restaging buf0
    {
      async16(Kbase + sr0 * 64 + sc0, &Ks[0][t * 8]);
      async16(Kbase + sr1 * 64 + sc1, &Ks[0][t * 8 + 2048]);
      async16(Vbase + (size_t)sr0 * 2048 + sc0, &Vs[0][t * 8]);
      async16(Vbase + (size_t)sr1 * 2048 + sc1, &Vs[0][t * 8 + 2048]);
    }

    for (int kt = 0; kt < nkt; ++kt) {
      const int cur = kt & 1;
      __syncthreads();  // buf[cur] staged; prev reads of buf[1-cur] done
      if (kt + 1 < nkt) {
        const int nxt = 1 - cur;
        const u16* kg = Kbase + (kt + 1) * 4096;
        async16(kg + sr0 * 64 + sc0, &Ks[nxt][t * 8]);
        async16(kg + sr1 * 64 + sc1, &Ks[nxt][t * 8 + 2048]);
        async16(Vbase + (size_t)sr0 * 2048 + (kt + 1) * 64 + sc0,
                &Vs[nxt][t * 8]);
        async16(Vbase + (size_t)sr1 * 2048 + (kt + 1) * 64 + sc1,
                &Vs[nxt][t * 8 + 2048]);
      }
      if (kt * 64 > qw + 31) continue;  // wave fully masked (uniform)
      const u16* Kb = Ks[cur];
      const u16* Vb = Vs[cur];

      // ---- S^T = K . Q^T ----
      f32x16 sT[2];
#pragma unroll
      for (int mt = 0; mt < 2; ++mt) {
        const int tilebase = kt * 64 + mt * 32;
        if (tilebase > qw + 31) continue;  // dead m-tile (P zeroed below)
#pragma unroll
        for (int r = 0; r < 16; ++r) sT[mt][r] = 0.f;
#pragma unroll
        for (int dep = 0; dep < 4; ++dep) {
          s16x8 kf = ld8(&Kb[mt * 2048 + swz[dep]]);
          sT[mt] = MFMA32(kf, qb[dep], sT[mt]);
        }
      }
      // ---- mask, exp2, lacc, pack P ----
#pragma unroll
      for (int mt = 0; mt < 2; ++mt) {
        const int tilebase = kt * 64 + mt * 32;
        const bool live = tilebase <= qw + 31;
        if (live && tilebase + 31 > qw) {  // diagonal tile: mask
          const int qa = qw + l31;
#pragma unroll
          for (int r = 0; r < 16; ++r) {
            int key = tilebase + (r & 3) + 8 * (r >> 2) + 4 * lh;
            if (key > qa) sT[mt][r] = -1e30f;
          }
        }
#pragma unroll
        for (int rq = 0; rq < 4; ++rq) {
          u32x2 pv;
          if (live) {
            float p0 = exp2f(sT[mt][rq * 4 + 0]);
            float p1 = exp2f(sT[mt][rq * 4 + 1]);
            float p2 = exp2f(sT[mt][rq * 4 + 2]);
            float p3 = exp2f(sT[mt][rq * 4 + 3]);
            lacc += (p0 + p1) + (p2 + p3);
            pv[0] = pkbf(p0, p1);
            pv[1] = pkbf(p2, p3);
          } else {
            pv[0] = 0u;
            pv[1] = 0u;
          }
          *(u32x2*)(&Ps[wof[mt * 4 + rq]]) = pv;
        }
      }
      // ---- O^T += V^T . P^T  (A=V^T rows, B=P rows; wave-private P) ----
      s16x8 pf[4];
#pragma unroll
      for (int dep = 0; dep < 4; ++dep)
        pf[dep] = ld8(&Ps[w * 2048 + swz[dep]]);
#pragma unroll
      for (int mt2 = 0; mt2 < 2; ++mt2)
#pragma unroll
        for (int dep = 0; dep < 4; ++dep) {
          s16x8 vf = ld8(&Vb[mt2 * 2048 + swz[dep]]);
          osum[mt2] = MFMA32(vf, pf[dep], osum[mt2]);
        }
    }

    // epilogue: l(q) = lacc(lane) + lacc(lane^32); store O[b][s][h*64+d]
    {
      float lt = lacc + __shfl_xor(lacc, 32);
      float inv = 1.f / lt;
      u16* obase = O + ((size_t)(b * 2048 + qw + l31)) * 2048 + h * 64;
#pragma unroll
      for (int mt2 = 0; mt2 < 2; ++mt2)
#pragma unroll
        for (int rq = 0; rq < 4; ++rq) {
          float v0 = osum[mt2][rq * 4 + 0] * inv;
          float v1 = osum[mt2][rq * 4 + 1] * inv;
          float v2 = osum[mt2][rq * 4 + 2] * inv;
          float v3 = osum[mt2][rq * 4 + 3] * inv;
          u16x4 ov = {f2bf(v0), f2bf(v1), f2bf(v2), f2bf(v3)};
          *(u16x4*)(obase + mt2 * 32 + rq * 8 + 4 * lh) = ov;
        }
    }
  }
}

// ---------------- launch ----------------
extern "C" void kernel_launch(void* const* d_in, const int* in_sizes, int n_in,
                              void* d_out, int out_size, void* d_ws,
                              size_t ws_size, hipStream_t stream) {
  const float* X = (const float*)d_in[0];
  const float* cosp = (const float*)d_in[1];
  const float* sinp = (const float*)d_in[2];
  const float* Wq = (const float*)d_in[4];
  const float* Wk = (const float*)d_in[5];
  const float* Wv = (const float*)d_in[6];
  const float* Wo = (const float*)d_in[7];
  float* out = (float*)d_out;

  u16* Xb = (u16*)d_ws;       // 8,388,608
  u16* Wqkv = Xb + 8388608;   // 3072x2048 (Wq|Wk|Wv rows)
  u16* Wob = Wqkv + 6291456;  // 4,194,304
  u16* Qr = Wob + 4194304;    // [2][32][2048][64]  (pre-scaled)
  u16* Kr = Qr + 8388608;     // [2][8][2048][64]
  u16* Vt = Kr + 2097152;     // [2][8][64][2048]
  u16* Ob = Vt + 2097152;     // [2][2048][2048]

  cvt_all<<<18432, 256, 0, stream>>>(X, Wq, Wk, Wv, Wo, Xb);

  gemm_nt<EPI_QKV, 128><<<dim3(24, 32), 256, 0, stream>>>(
      Xb, Wqkv, cosp, sinp, Qr, Kr, Vt, nullptr, 2048);

  attn<<<dim3(8, 64), 256, 0, stream>>>(Qr, Kr, Vt, Ob);

  gemm_nt<EPI_OUT, 64><<<dim3(32, 32), 256, 0, stream>>>(
      Ob, Wob, nullptr, nullptr, nullptr, nullptr, nullptr, out, 2048);
}